// Round 3
// baseline (905.980 us; speedup 1.0000x reference)
//
#include <hip/hip_runtime.h>
#include <math.h>

#define EPSF 1e-8f
#define SINH_MAXF 11.090354888959125f
#define IMAGE_ALPHA 0.25f
#define TEXT_ALPHA (1.0f/0.6f)
#define LOGIT_SCALE (1.0f/0.07f)
#define LN2F 0.6931471805599453f
#define ENTAIL_WEIGHT 0.2f
#define NCLS 151
#define NPAD 160
#define DIM 64

// ws float offsets
#define LMIN_OFF 8   // log2(2*min_c y_time)
#define YT_OFF 16
#define XN_OFF (YT_OFF + NPAD)
#define AP_OFF (XN_OFF + NPAD)
#define BT_OFF 512   // bf16 protos [160][64] = 20480 B, 16B-aligned

typedef __attribute__((ext_vector_type(8))) short bf16x8;
typedef __attribute__((ext_vector_type(4))) float f32x4;

__device__ inline unsigned short f2bf(float f) {
    unsigned int u = __float_as_uint(f);
    return (unsigned short)((u + 0x7FFFu + ((u >> 16) & 1u)) >> 16);
}

__device__ inline float sel4(const float* a, int i) {
    return i == 0 ? a[0] : i == 1 ? a[1] : i == 2 ? a[2] : a[3];
}

__global__ void proto_kernel(const float* __restrict__ protos, float* __restrict__ ws) {
    int c = blockIdx.x, d = threadIdx.x;
    unsigned short* bt = (unsigned short*)(ws + BT_OFF);
    if (c >= NCLS) {
        bt[c * DIM + d] = 0;
        if (d == 0) { ws[YT_OFF + c] = 2e18f; ws[XN_OFF + c] = 1.f; ws[AP_OFF + c] = 0.f; }
        return;
    }
    float v = protos[c * DIM + d] * TEXT_ALPHA;
    float n2 = v * v;
    #pragma unroll
    for (int m = 32; m >= 1; m >>= 1) n2 += __shfl_xor(n2, m, 64);
    float rc = sqrtf(n2);
    float sh = sinhf(fminf(fmaxf(rc, EPSF), SINH_MAXF));
    float sc = sh / fmaxf(rc, EPSF);
    bt[c * DIM + d] = f2bf(sc * v);
    if (d == 0) {
        float xn = sc * rc;
        ws[YT_OFF + c] = sqrtf(1.f + xn * xn);
        ws[XN_OFF + c] = xn;
        float ai = 0.2f / (xn + EPSF);
        ai = fminf(fmaxf(ai, -1.f + EPSF), 1.f - EPSF);
        ws[AP_OFF + c] = asinf(ai);
    }
}

__global__ void minyt_kernel(float* ws) {
    int lane = threadIdx.x;
    float m = 1e30f;
    for (int c = lane; c < NCLS; c += 64) m = fminf(m, ws[YT_OFF + c]);
    #pragma unroll
    for (int k = 32; k >= 1; k >>= 1) m = fminf(m, __shfl_xor(m, k, 64));
    if (lane == 0) ws[LMIN_OFF] = __log2f(2.f * m);
}

__global__ __launch_bounds__(256) void main_kernel(
    const float* __restrict__ feats, const int* __restrict__ labels,
    const unsigned char* __restrict__ mask, const float* __restrict__ wsro,
    float* acc)
{
    int wid = threadIdx.x >> 6, lane = threadIdx.x & 63;
    int cn = lane & 15;       // pixel-in-tile (A row) AND class-in-tile (B col)
    int g  = lane >> 4;       // k-group
    int wavebase = (blockIdx.x * 4 + wid) * 16;
    int pix = wavebase + cn;

    float lmin2 = wsro[LMIN_OFF];   // log2(2*yt_min), wave-uniform

    // ---- A staging: lane holds pixel `cn`, dims [g*8,+8) and [32+g*8,+8) ----
    const float4* fp = (const float4*)(feats + (size_t)pix * DIM + g * 8);
    float4 a0 = fp[0], a1 = fp[1], b0 = fp[8], b1 = fp[9];
    a0.x *= IMAGE_ALPHA; a0.y *= IMAGE_ALPHA; a0.z *= IMAGE_ALPHA; a0.w *= IMAGE_ALPHA;
    a1.x *= IMAGE_ALPHA; a1.y *= IMAGE_ALPHA; a1.z *= IMAGE_ALPHA; a1.w *= IMAGE_ALPHA;
    b0.x *= IMAGE_ALPHA; b0.y *= IMAGE_ALPHA; b0.z *= IMAGE_ALPHA; b0.w *= IMAGE_ALPHA;
    b1.x *= IMAGE_ALPHA; b1.y *= IMAGE_ALPHA; b1.z *= IMAGE_ALPHA; b1.w *= IMAGE_ALPHA;
    float n2 = a0.x*a0.x + a0.y*a0.y + a0.z*a0.z + a0.w*a0.w
             + a1.x*a1.x + a1.y*a1.y + a1.z*a1.z + a1.w*a1.w
             + b0.x*b0.x + b0.y*b0.y + b0.z*b0.z + b0.w*b0.w
             + b1.x*b1.x + b1.y*b1.y + b1.z*b1.z + b1.w*b1.w;
    n2 += __shfl_xor(n2, 16, 64);
    n2 += __shfl_xor(n2, 32, 64);     // all 4 owner-lanes of this pixel have full n2
    float rc = sqrtf(n2);
    float sh = sinhf(fminf(fmaxf(rc, EPSF), SINH_MAXF));
    float sc = sh / fmaxf(rc, EPSF);
    float xnorm = sc * rc;
    float xt = sqrtf(fmaf(xnorm, xnorm, 1.f));          // image time coord
    // per-pixel conservative logit offset (log2 domain): b2 >= S*log2(2z) for all classes
    float b2_own = LOGIT_SCALE * (lmin2 - __log2f(xt + xnorm));

    bf16x8 aq0, aq1;
    aq0[0] = (short)f2bf(sc * a0.x); aq0[1] = (short)f2bf(sc * a0.y);
    aq0[2] = (short)f2bf(sc * a0.z); aq0[3] = (short)f2bf(sc * a0.w);
    aq0[4] = (short)f2bf(sc * a1.x); aq0[5] = (short)f2bf(sc * a1.y);
    aq0[6] = (short)f2bf(sc * a1.z); aq0[7] = (short)f2bf(sc * a1.w);
    aq1[0] = (short)f2bf(sc * b0.x); aq1[1] = (short)f2bf(sc * b0.y);
    aq1[2] = (short)f2bf(sc * b0.z); aq1[3] = (short)f2bf(sc * b0.w);
    aq1[4] = (short)f2bf(sc * b1.x); aq1[5] = (short)f2bf(sc * b1.y);
    aq1[6] = (short)f2bf(sc * b1.z); aq1[7] = (short)f2bf(sc * b1.w);

    // distribute per-row (C rows r = g*4+reg ↔ pixel wavebase+g*4+r) state
    int lab_own = labels[pix];
    float xtr[4], br[4]; int labr[4];
    #pragma unroll
    for (int r = 0; r < 4; r++) {
        xtr[r]  = __shfl(xt, g * 4 + r, 64);
        br[r]   = __shfl(b2_own, g * 4 + r, 64);
        labr[r] = __shfl(lab_own, g * 4 + r, 64);
    }

    const uint4* bt = (const uint4*)(wsro + BT_OFF);
    const float* ytp = wsro + YT_OFF;
    float ss[4] = {0.f, 0.f, 0.f, 0.f};
    float cxl_lab[4] = {0.f, 0.f, 0.f, 0.f};

    #pragma unroll 2
    for (int t = 0; t < 10; t++) {
        int cls = t * 16 + cn;
        uint4 r0 = bt[cls * 8 + g];          // dims g*8..+7
        uint4 r1 = bt[cls * 8 + 4 + g];      // dims 32+g*8..+7
        float yt = ytp[cls];
        bf16x8 bq0 = __builtin_bit_cast(bf16x8, r0);
        bf16x8 bq1 = __builtin_bit_cast(bf16x8, r1);
        f32x4 d = {0.f, 0.f, 0.f, 0.f};
        d = __builtin_amdgcn_mfma_f32_16x16x32_bf16(aq0, bq0, d, 0, 0, 0);
        d = __builtin_amdgcn_mfma_f32_16x16x32_bf16(aq1, bq1, d, 0, 0, 0);
        #pragma unroll
        for (int r = 0; r < 4; r++) {
            float cxl = fmaf(xtr[r], yt, -d[r]);          // x_time*y_time - dot
            if (labr[r] == cls) cxl_lab[r] = cxl;
            float z = fmaxf(cxl, 1.f + EPSF);
            float u = __log2f(z + z);                     // log2(2z) ~ acosh/ln2
            ss[r] += exp2f(fmaf(-LOGIT_SCALE, u, br[r])); // exp(logit - M0)
        }
    }

    // merge partial sums / label-cxl across the 16-lane class dimension
    #pragma unroll
    for (int k = 1; k < 16; k <<= 1) {
        #pragma unroll
        for (int r = 0; r < 4; r++) {
            ss[r] += __shfl_xor(ss[r], k, 64);
            cxl_lab[r] = fmaxf(cxl_lab[r], __shfl_xor(cxl_lab[r], k, 64));
        }
    }

    // ---- epilogue: lanes cn<4 finalize pixel wavebase + g*4 + cn ----
    float v_nll = 0.f, v_ent = 0.f, valid = 0.f;
    if (cn < 4) {
        float T   = sel4(ss, cn);
        float cxl = sel4(cxl_lab, cn);
        float xts = sel4(xtr, cn);
        float b2  = sel4(br, cn);
        int lb = cn == 0 ? labr[0] : cn == 1 ? labr[1] : cn == 2 ? labr[2] : labr[3];
        int pr = wavebase + g * 4 + cn;
        float u_lab = __log2f(2.f * fmaxf(cxl, 1.f + EPSF));
        float nll = LN2F * (__log2f(T) - b2 + LOGIT_SCALE * u_lab);
        float pt = wsro[YT_OFF + lb], pn = wsro[XN_OFF + lb], ap = wsro[AP_OFF + lb];
        float num = fmaf(-cxl, pt, xts);                   // y_time + c_xyl*x_time
        float den = pn * sqrtf(fmaxf(fmaf(cxl, cxl, -1.f), 0.f));
        float ain = num / (den + EPSF);
        ain = fminf(fmaxf(ain, -1.f + EPSF), 1.f - EPSF);
        float ent = fmaxf(acosf(ain) - ap, 0.f);
        valid = mask[pr] ? 0.f : 1.f;
        v_nll = nll * valid;
        v_ent = ent * valid;
    }

    // ---- wave + block reduce, 3 atomics per block ----
    #pragma unroll
    for (int o = 32; o >= 1; o >>= 1) {
        v_nll += __shfl_down(v_nll, o, 64);
        v_ent += __shfl_down(v_ent, o, 64);
        valid += __shfl_down(valid, o, 64);
    }
    __shared__ float red[3][4];
    if (lane == 0) { red[0][wid] = v_nll; red[1][wid] = v_ent; red[2][wid] = valid; }
    __syncthreads();
    if (threadIdx.x == 0) {
        float a = 0.f, b = 0.f, c = 0.f;
        #pragma unroll
        for (int w = 0; w < 4; w++) { a += red[0][w]; b += red[1][w]; c += red[2][w]; }
        atomicAdd(&acc[0], a);
        atomicAdd(&acc[1], b);
        atomicAdd(&acc[2], c);
    }
}

__global__ void final_kernel(const float* acc, float* out) {
    float n = fmaxf(acc[2], 1.0f);
    out[0] = acc[0] / n + ENTAIL_WEIGHT * (acc[1] / n);
}

extern "C" void kernel_launch(void* const* d_in, const int* in_sizes, int n_in,
                              void* d_out, int out_size, void* d_ws, size_t ws_size,
                              hipStream_t stream) {
    const float* feats  = (const float*)d_in[0];
    const float* protos = (const float*)d_in[1];
    const int* labels   = (const int*)d_in[2];
    const unsigned char* mask = (const unsigned char*)d_in[3];  // numpy bool = 1 byte
    float* ws = (float*)d_ws;

    hipMemsetAsync(ws, 0, 16 * sizeof(float), stream);
    proto_kernel<<<NPAD, DIM, 0, stream>>>(protos, ws);
    minyt_kernel<<<1, 64, 0, stream>>>(ws);

    int npix = in_sizes[2];                 // B*H*W = 524288
    int nblk = npix / 64;                   // 4 waves/block, 16 pixels/wave
    main_kernel<<<nblk, 256, 0, stream>>>(feats, labels, mask, ws, ws);
    final_kernel<<<1, 1, 0, stream>>>(ws, (float*)d_out);
}

// Round 4
// 270.600 us; speedup vs baseline: 3.3480x; 3.3480x over previous
//
#include <hip/hip_runtime.h>
#include <math.h>

#define EPSF 1e-8f
#define SINH_MAXF 11.090354888959125f
#define IMAGE_ALPHA 0.25f
#define TEXT_ALPHA (1.0f/0.6f)
#define LOGIT_SCALE (1.0f/0.07f)
#define LN2F 0.6931471805599453f
#define ENTAIL_WEIGHT 0.2f
#define NCLS 151
#define NPAD 160
#define DIM 64
#define NBLK 8192

// ws float offsets
#define LMIN_OFF 8   // log2(2*min_c y_time)
#define YT_OFF 16
#define XN_OFF (YT_OFF + NPAD)
#define AP_OFF (XN_OFF + NPAD)
#define BT_OFF 512                    // bf16 protos [160][64] = 20480 B
#define BLK_OFF (BT_OFF + NPAD*DIM/2) // per-block float4 partials, 8192*4 floats

typedef __attribute__((ext_vector_type(8))) short bf16x8;
typedef __attribute__((ext_vector_type(4))) float f32x4;

__device__ inline unsigned short f2bf(float f) {
    unsigned int u = __float_as_uint(f);
    return (unsigned short)((u + 0x7FFFu + ((u >> 16) & 1u)) >> 16);
}

__device__ inline float sel4(const float* a, int i) {
    return i == 0 ? a[0] : i == 1 ? a[1] : i == 2 ? a[2] : a[3];
}

__global__ void proto_kernel(const float* __restrict__ protos, float* __restrict__ ws) {
    int c = blockIdx.x, d = threadIdx.x;
    unsigned short* bt = (unsigned short*)(ws + BT_OFF);
    if (c >= NCLS) {
        bt[c * DIM + d] = 0;
        if (d == 0) { ws[YT_OFF + c] = 2e18f; ws[XN_OFF + c] = 1.f; ws[AP_OFF + c] = 0.f; }
        return;
    }
    float v = protos[c * DIM + d] * TEXT_ALPHA;
    float n2 = v * v;
    #pragma unroll
    for (int m = 32; m >= 1; m >>= 1) n2 += __shfl_xor(n2, m, 64);
    float rc = sqrtf(n2);
    float sh = sinhf(fminf(fmaxf(rc, EPSF), SINH_MAXF));
    float sc = sh / fmaxf(rc, EPSF);
    bt[c * DIM + d] = f2bf(sc * v);
    if (d == 0) {
        float xn = sc * rc;
        ws[YT_OFF + c] = sqrtf(1.f + xn * xn);
        ws[XN_OFF + c] = xn;
        float ai = 0.2f / (xn + EPSF);
        ai = fminf(fmaxf(ai, -1.f + EPSF), 1.f - EPSF);
        ws[AP_OFF + c] = asinf(ai);
    }
}

__global__ void minyt_kernel(float* ws) {
    int lane = threadIdx.x;
    float m = 1e30f;
    for (int c = lane; c < NCLS; c += 64) m = fminf(m, ws[YT_OFF + c]);
    #pragma unroll
    for (int k = 32; k >= 1; k >>= 1) m = fminf(m, __shfl_xor(m, k, 64));
    if (lane == 0) ws[LMIN_OFF] = __log2f(2.f * m);
}

__global__ __launch_bounds__(256) void main_kernel(
    const float* __restrict__ feats, const int* __restrict__ labels,
    const unsigned char* __restrict__ mask, const float* __restrict__ wsro,
    float4* __restrict__ blkout)
{
    int wid = threadIdx.x >> 6, lane = threadIdx.x & 63;
    int cn = lane & 15;       // pixel-in-tile (A row) AND class-in-tile (B col)
    int g  = lane >> 4;       // k-group
    int wavebase = (blockIdx.x * 4 + wid) * 16;
    int pix = wavebase + cn;

    float lmin2 = wsro[LMIN_OFF];   // log2(2*yt_min), wave-uniform

    // ---- A staging: lane holds pixel `cn`, dims [g*8,+8) and [32+g*8,+8) ----
    const float4* fp = (const float4*)(feats + (size_t)pix * DIM + g * 8);
    float4 a0 = fp[0], a1 = fp[1], b0 = fp[8], b1 = fp[9];
    a0.x *= IMAGE_ALPHA; a0.y *= IMAGE_ALPHA; a0.z *= IMAGE_ALPHA; a0.w *= IMAGE_ALPHA;
    a1.x *= IMAGE_ALPHA; a1.y *= IMAGE_ALPHA; a1.z *= IMAGE_ALPHA; a1.w *= IMAGE_ALPHA;
    b0.x *= IMAGE_ALPHA; b0.y *= IMAGE_ALPHA; b0.z *= IMAGE_ALPHA; b0.w *= IMAGE_ALPHA;
    b1.x *= IMAGE_ALPHA; b1.y *= IMAGE_ALPHA; b1.z *= IMAGE_ALPHA; b1.w *= IMAGE_ALPHA;
    float n2 = a0.x*a0.x + a0.y*a0.y + a0.z*a0.z + a0.w*a0.w
             + a1.x*a1.x + a1.y*a1.y + a1.z*a1.z + a1.w*a1.w
             + b0.x*b0.x + b0.y*b0.y + b0.z*b0.z + b0.w*b0.w
             + b1.x*b1.x + b1.y*b1.y + b1.z*b1.z + b1.w*b1.w;
    n2 += __shfl_xor(n2, 16, 64);
    n2 += __shfl_xor(n2, 32, 64);     // all 4 owner-lanes of this pixel have full n2
    float rc = sqrtf(n2);
    float sh = sinhf(fminf(fmaxf(rc, EPSF), SINH_MAXF));
    float sc = sh / fmaxf(rc, EPSF);
    float xnorm = sc * rc;
    float xt = sqrtf(fmaf(xnorm, xnorm, 1.f));          // image time coord
    // per-pixel conservative logit offset (log2 domain): b2 >= S*log2(2z) for all classes
    float b2_own = LOGIT_SCALE * (lmin2 - __log2f(xt + xnorm));

    bf16x8 aq0, aq1;
    aq0[0] = (short)f2bf(sc * a0.x); aq0[1] = (short)f2bf(sc * a0.y);
    aq0[2] = (short)f2bf(sc * a0.z); aq0[3] = (short)f2bf(sc * a0.w);
    aq0[4] = (short)f2bf(sc * a1.x); aq0[5] = (short)f2bf(sc * a1.y);
    aq0[6] = (short)f2bf(sc * a1.z); aq0[7] = (short)f2bf(sc * a1.w);
    aq1[0] = (short)f2bf(sc * b0.x); aq1[1] = (short)f2bf(sc * b0.y);
    aq1[2] = (short)f2bf(sc * b0.z); aq1[3] = (short)f2bf(sc * b0.w);
    aq1[4] = (short)f2bf(sc * b1.x); aq1[5] = (short)f2bf(sc * b1.y);
    aq1[6] = (short)f2bf(sc * b1.z); aq1[7] = (short)f2bf(sc * b1.w);

    // distribute per-row (C rows r = g*4+reg ↔ pixel wavebase+g*4+r) state
    int lab_own = labels[pix];
    float xtr[4], br[4]; int labr[4];
    #pragma unroll
    for (int r = 0; r < 4; r++) {
        xtr[r]  = __shfl(xt, g * 4 + r, 64);
        br[r]   = __shfl(b2_own, g * 4 + r, 64);
        labr[r] = __shfl(lab_own, g * 4 + r, 64);
    }

    const uint4* bt = (const uint4*)(wsro + BT_OFF);
    const float* ytp = wsro + YT_OFF;
    float ss[4] = {0.f, 0.f, 0.f, 0.f};
    float cxl_lab[4] = {0.f, 0.f, 0.f, 0.f};

    #pragma unroll 2
    for (int t = 0; t < 10; t++) {
        int cls = t * 16 + cn;
        uint4 r0 = bt[cls * 8 + g];          // dims g*8..+7
        uint4 r1 = bt[cls * 8 + 4 + g];      // dims 32+g*8..+7
        float yt = ytp[cls];
        bf16x8 bq0 = __builtin_bit_cast(bf16x8, r0);
        bf16x8 bq1 = __builtin_bit_cast(bf16x8, r1);
        f32x4 d = {0.f, 0.f, 0.f, 0.f};
        d = __builtin_amdgcn_mfma_f32_16x16x32_bf16(aq0, bq0, d, 0, 0, 0);
        d = __builtin_amdgcn_mfma_f32_16x16x32_bf16(aq1, bq1, d, 0, 0, 0);
        #pragma unroll
        for (int r = 0; r < 4; r++) {
            float cxl = fmaf(xtr[r], yt, -d[r]);          // x_time*y_time - dot
            if (labr[r] == cls) cxl_lab[r] = cxl;
            float z = fmaxf(cxl, 1.f + EPSF);
            float u = __log2f(z + z);                     // log2(2z) ~ acosh/ln2
            ss[r] += exp2f(fmaf(-LOGIT_SCALE, u, br[r])); // exp(logit - M0)
        }
    }

    // merge partial sums / label-cxl across the 16-lane class dimension
    #pragma unroll
    for (int k = 1; k < 16; k <<= 1) {
        #pragma unroll
        for (int r = 0; r < 4; r++) {
            ss[r] += __shfl_xor(ss[r], k, 64);
            cxl_lab[r] = fmaxf(cxl_lab[r], __shfl_xor(cxl_lab[r], k, 64));
        }
    }

    // ---- epilogue: lanes cn<4 finalize pixel wavebase + g*4 + cn ----
    float v_nll = 0.f, v_ent = 0.f, valid = 0.f;
    if (cn < 4) {
        float T   = sel4(ss, cn);
        float cxl = sel4(cxl_lab, cn);
        float xts = sel4(xtr, cn);
        float b2  = sel4(br, cn);
        int lb = cn == 0 ? labr[0] : cn == 1 ? labr[1] : cn == 2 ? labr[2] : labr[3];
        int pr = wavebase + g * 4 + cn;
        float u_lab = __log2f(2.f * fmaxf(cxl, 1.f + EPSF));
        float nll = LN2F * (__log2f(T) - b2 + LOGIT_SCALE * u_lab);
        float pt = wsro[YT_OFF + lb], pn = wsro[XN_OFF + lb], ap = wsro[AP_OFF + lb];
        float num = fmaf(-cxl, pt, xts);                   // y_time + c_xyl*x_time
        float den = pn * sqrtf(fmaxf(fmaf(cxl, cxl, -1.f), 0.f));
        float ain = num / (den + EPSF);
        ain = fminf(fmaxf(ain, -1.f + EPSF), 1.f - EPSF);
        float ent = fmaxf(acosf(ain) - ap, 0.f);
        valid = mask[pr] ? 0.f : 1.f;
        v_nll = nll * valid;
        v_ent = ent * valid;
    }

    // ---- wave + block reduce, ONE float4 store per block (no atomics) ----
    #pragma unroll
    for (int o = 32; o >= 1; o >>= 1) {
        v_nll += __shfl_down(v_nll, o, 64);
        v_ent += __shfl_down(v_ent, o, 64);
        valid += __shfl_down(valid, o, 64);
    }
    __shared__ float red[3][4];
    if (lane == 0) { red[0][wid] = v_nll; red[1][wid] = v_ent; red[2][wid] = valid; }
    __syncthreads();
    if (threadIdx.x == 0) {
        float a = 0.f, b = 0.f, c = 0.f;
        #pragma unroll
        for (int w = 0; w < 4; w++) { a += red[0][w]; b += red[1][w]; c += red[2][w]; }
        blkout[blockIdx.x] = make_float4(a, b, c, 0.f);
    }
}

__global__ __launch_bounds__(1024) void reduce_kernel(const float4* __restrict__ blk,
                                                      float* __restrict__ out) {
    float a = 0.f, b = 0.f, c = 0.f;
    for (int i = threadIdx.x; i < NBLK; i += 1024) {
        float4 v = blk[i];
        a += v.x; b += v.y; c += v.z;
    }
    #pragma unroll
    for (int o = 32; o >= 1; o >>= 1) {
        a += __shfl_down(a, o, 64);
        b += __shfl_down(b, o, 64);
        c += __shfl_down(c, o, 64);
    }
    __shared__ float red[3][16];
    int wid = threadIdx.x >> 6, lane = threadIdx.x & 63;
    if (lane == 0) { red[0][wid] = a; red[1][wid] = b; red[2][wid] = c; }
    __syncthreads();
    if (threadIdx.x == 0) {
        float A = 0.f, B = 0.f, C = 0.f;
        #pragma unroll
        for (int w = 0; w < 16; w++) { A += red[0][w]; B += red[1][w]; C += red[2][w]; }
        float n = fmaxf(C, 1.f);
        out[0] = A / n + ENTAIL_WEIGHT * (B / n);
    }
}

extern "C" void kernel_launch(void* const* d_in, const int* in_sizes, int n_in,
                              void* d_out, int out_size, void* d_ws, size_t ws_size,
                              hipStream_t stream) {
    const float* feats  = (const float*)d_in[0];
    const float* protos = (const float*)d_in[1];
    const int* labels   = (const int*)d_in[2];
    const unsigned char* mask = (const unsigned char*)d_in[3];  // numpy bool = 1 byte
    float* ws = (float*)d_ws;

    proto_kernel<<<NPAD, DIM, 0, stream>>>(protos, ws);
    minyt_kernel<<<1, 64, 0, stream>>>(ws);

    int npix = in_sizes[2];                 // B*H*W = 524288
    int nblk = npix / 64;                   // 4 waves/block, 16 pixels/wave
    main_kernel<<<nblk, 256, 0, stream>>>(feats, labels, mask, ws,
                                          (float4*)(ws + BLK_OFF));
    reduce_kernel<<<1, 1024, 0, stream>>>((const float4*)(ws + BLK_OFF), (float*)d_out);
}

// Round 5
// 241.237 us; speedup vs baseline: 3.7556x; 1.1217x over previous
//
#include <hip/hip_runtime.h>
#include <math.h>

#define EPSF 1e-8f
#define SINH_MAXF 11.090354888959125f
#define IMAGE_ALPHA 0.25f
#define TEXT_ALPHA (1.0f/0.6f)
#define LOGIT_SCALE (1.0f/0.07f)
#define LN2F 0.6931471805599453f
#define SLN (LOGIT_SCALE*LN2F)
#define ENTAIL_WEIGHT 0.2f
#define NCLS 151
#define NPAD 160
#define DIM 64
#define NBLK 4096

// ws float offsets
#define LMIN_OFF 8   // log2(2*min_c y_time)
#define YT_OFF 16
#define XN_OFF (YT_OFF + NPAD)
#define AP_OFF (XN_OFF + NPAD)
#define BT_OFF 512                    // bf16 protos, MFMA-fragment order, 20480 B
#define BLK_OFF (BT_OFF + NPAD*DIM/2) // per-block float4 partials

typedef __attribute__((ext_vector_type(8))) short bf16x8;
typedef __attribute__((ext_vector_type(4))) float f32x4;

__device__ inline unsigned short f2bf(float f) {
    unsigned int u = __float_as_uint(f);
    return (unsigned short)((u + 0x7FFFu + ((u >> 16) & 1u)) >> 16);
}
__device__ inline float sel4(const float* a, int i) {
    return i == 0 ? a[0] : i == 1 ? a[1] : i == 2 ? a[2] : a[3];
}
__device__ inline int isel4(const int* a, int i) {
    return i == 0 ? a[0] : i == 1 ? a[1] : i == 2 ? a[2] : a[3];
}

// Single block. Writes protos in MFMA B-fragment order:
// 16B unit index = t*128 + half*64 + (g*16+cn), element j: class t*16+cn, dim half*32+g*8+j
__global__ __launch_bounds__(256) void proto_kernel(const float* __restrict__ protos,
                                                    float* __restrict__ ws) {
    int tid = threadIdx.x, w = tid >> 6, l = tid & 63;
    unsigned short* bt = (unsigned short*)(ws + BT_OFF);
    __shared__ float sYT[NPAD];
    for (int c = w; c < NPAD; c += 4) {
        int t = c >> 4, cn = c & 15;
        int half = l >> 5, g = (l >> 3) & 3, j = l & 7;
        int sidx = (t * 128 + half * 64 + g * 16 + cn) * 8 + j;
        float yt_c;
        if (c < NCLS) {
            float v = protos[c * DIM + l] * TEXT_ALPHA;
            float n2 = v * v;
            #pragma unroll
            for (int m = 32; m >= 1; m >>= 1) n2 += __shfl_xor(n2, m, 64);
            float rc = __builtin_amdgcn_sqrtf(n2);
            float rr = fminf(fmaxf(rc, EPSF), SINH_MAXF);
            float e = __expf(rr);
            float sh = 0.5f * (e - __builtin_amdgcn_rcpf(e));
            float sc = sh * __builtin_amdgcn_rcpf(fmaxf(rc, EPSF));
            bt[sidx] = f2bf(sc * v);
            float xn = sc * rc;
            yt_c = __builtin_amdgcn_sqrtf(fmaf(xn, xn, 1.f));
            if (l == 0) {
                ws[YT_OFF + c] = yt_c;
                ws[XN_OFF + c] = xn;
                float ai = fminf(fmaxf(0.2f / (xn + EPSF), -1.f + EPSF), 1.f - EPSF);
                ws[AP_OFF + c] = asinf(ai);
            }
        } else {
            bt[sidx] = 0;
            yt_c = 2e18f;
            if (l == 0) { ws[YT_OFF + c] = 2e18f; ws[XN_OFF + c] = 1.f; ws[AP_OFF + c] = 0.f; }
        }
        if (l == 0) sYT[c] = yt_c;
    }
    __syncthreads();
    if (tid < 64) {
        float m = 1e30f;
        for (int c = tid; c < NCLS; c += 64) m = fminf(m, sYT[c]);
        #pragma unroll
        for (int k = 32; k >= 1; k >>= 1) m = fminf(m, __shfl_xor(m, k, 64));
        if (tid == 0) ws[LMIN_OFF] = __log2f(2.f * m);
    }
}

struct PixA { bf16x8 q0, q1; float xt, Q; };

__device__ inline PixA stage_pixel(const float4* fp, float lmin2) {
    float4 a0 = fp[0], a1 = fp[1], b0 = fp[8], b1 = fp[9];
    a0.x *= IMAGE_ALPHA; a0.y *= IMAGE_ALPHA; a0.z *= IMAGE_ALPHA; a0.w *= IMAGE_ALPHA;
    a1.x *= IMAGE_ALPHA; a1.y *= IMAGE_ALPHA; a1.z *= IMAGE_ALPHA; a1.w *= IMAGE_ALPHA;
    b0.x *= IMAGE_ALPHA; b0.y *= IMAGE_ALPHA; b0.z *= IMAGE_ALPHA; b0.w *= IMAGE_ALPHA;
    b1.x *= IMAGE_ALPHA; b1.y *= IMAGE_ALPHA; b1.z *= IMAGE_ALPHA; b1.w *= IMAGE_ALPHA;
    float n2 = a0.x*a0.x + a0.y*a0.y + a0.z*a0.z + a0.w*a0.w
             + a1.x*a1.x + a1.y*a1.y + a1.z*a1.z + a1.w*a1.w
             + b0.x*b0.x + b0.y*b0.y + b0.z*b0.z + b0.w*b0.w
             + b1.x*b1.x + b1.y*b1.y + b1.z*b1.z + b1.w*b1.w;
    n2 += __shfl_xor(n2, 16, 64);
    n2 += __shfl_xor(n2, 32, 64);         // 4 owner-lanes of this pixel have full n2
    float rc = __builtin_amdgcn_sqrtf(n2);
    float rr = fminf(fmaxf(rc, EPSF), SINH_MAXF);
    float e = __expf(rr);
    float sh = 0.5f * (e - __builtin_amdgcn_rcpf(e));
    float sc = sh * __builtin_amdgcn_rcpf(fmaxf(rc, EPSF));
    float xn = sc * rc;
    PixA r;
    r.xt = __builtin_amdgcn_sqrtf(fmaf(xn, xn, 1.f));
    // nat-domain constant: Q = ln2*b2 - SLN, b2 = S*(lmin2 - log2(xt+xn))
    r.Q = SLN * (lmin2 - __log2f(r.xt + xn)) - SLN;
    r.q0[0] = (short)f2bf(sc*a0.x); r.q0[1] = (short)f2bf(sc*a0.y);
    r.q0[2] = (short)f2bf(sc*a0.z); r.q0[3] = (short)f2bf(sc*a0.w);
    r.q0[4] = (short)f2bf(sc*a1.x); r.q0[5] = (short)f2bf(sc*a1.y);
    r.q0[6] = (short)f2bf(sc*a1.z); r.q0[7] = (short)f2bf(sc*a1.w);
    r.q1[0] = (short)f2bf(sc*b0.x); r.q1[1] = (short)f2bf(sc*b0.y);
    r.q1[2] = (short)f2bf(sc*b0.z); r.q1[3] = (short)f2bf(sc*b0.w);
    r.q1[4] = (short)f2bf(sc*b1.x); r.q1[5] = (short)f2bf(sc*b1.y);
    r.q1[6] = (short)f2bf(sc*b1.z); r.q1[7] = (short)f2bf(sc*b1.w);
    return r;
}

__global__ __launch_bounds__(256) void main_kernel(
    const float* __restrict__ feats, const int* __restrict__ labels,
    const unsigned char* __restrict__ mask, const float* __restrict__ wsro,
    float4* __restrict__ blkout)
{
    __shared__ uint4 sBT[1280];     // 20480 B, fragment order
    __shared__ float sYT[NPAD];
    int tid = threadIdx.x;
    const uint4* btg = (const uint4*)(wsro + BT_OFF);
    #pragma unroll
    for (int k = 0; k < 5; k++) sBT[tid + k * 256] = btg[tid + k * 256];
    if (tid < NPAD) sYT[tid] = wsro[YT_OFF + tid];
    __syncthreads();

    int wid = tid >> 6, lane = tid & 63;
    int cn = lane & 15, g = lane >> 4;
    int wavebase = (blockIdx.x * 4 + wid) * 32;
    int pix0 = wavebase + cn, pix1 = pix0 + 16;
    float lmin2 = wsro[LMIN_OFF];

    PixA A0 = stage_pixel((const float4*)(feats + (size_t)pix0 * DIM + g * 8), lmin2);
    PixA A1 = stage_pixel((const float4*)(feats + (size_t)pix1 * DIM + g * 8), lmin2);
    int lab0 = labels[pix0], lab1 = labels[pix1];

    float xtr0[4], Q0[4], xtr1[4], Q1[4];
    int lr0[4], lr1[4];
    #pragma unroll
    for (int r = 0; r < 4; r++) {
        int src = g * 4 + r;
        xtr0[r] = __shfl(A0.xt, src, 64); Q0[r] = __shfl(A0.Q, src, 64);
        lr0[r]  = __shfl(lab0, src, 64);
        xtr1[r] = __shfl(A1.xt, src, 64); Q1[r] = __shfl(A1.Q, src, 64);
        lr1[r]  = __shfl(lab1, src, 64);
    }

    float ss0[4] = {0,0,0,0}, ss1[4] = {0,0,0,0};
    float cx0[4] = {0,0,0,0}, cx1[4] = {0,0,0,0};

    #pragma unroll 2
    for (int t = 0; t < 10; t++) {
        uint4 u0 = sBT[t * 128 + lane];
        uint4 u1 = sBT[t * 128 + 64 + lane];
        bf16x8 bq0 = __builtin_bit_cast(bf16x8, u0);
        bf16x8 bq1 = __builtin_bit_cast(bf16x8, u1);
        float yt = sYT[t * 16 + cn];
        int cls = t * 16 + cn;
        f32x4 d0 = {0,0,0,0}, d1 = {0,0,0,0};
        d0 = __builtin_amdgcn_mfma_f32_16x16x32_bf16(A0.q0, bq0, d0, 0, 0, 0);
        d0 = __builtin_amdgcn_mfma_f32_16x16x32_bf16(A0.q1, bq1, d0, 0, 0, 0);
        d1 = __builtin_amdgcn_mfma_f32_16x16x32_bf16(A1.q0, bq0, d1, 0, 0, 0);
        d1 = __builtin_amdgcn_mfma_f32_16x16x32_bf16(A1.q1, bq1, d1, 0, 0, 0);
        #pragma unroll
        for (int r = 0; r < 4; r++) {
            float c0 = fmaf(xtr0[r], yt, -d0[r]);         // x_time*y_time - dot
            if (lr0[r] == cls) cx0[r] = c0;
            float u0f = __log2f(fmaxf(c0, 1.f + EPSF));
            ss0[r] += __expf(fmaf(-SLN, u0f, Q0[r]));     // exp(logit - M0)
            float c1 = fmaf(xtr1[r], yt, -d1[r]);
            if (lr1[r] == cls) cx1[r] = c1;
            float u1f = __log2f(fmaxf(c1, 1.f + EPSF));
            ss1[r] += __expf(fmaf(-SLN, u1f, Q1[r]));
        }
    }

    #pragma unroll
    for (int k = 1; k < 16; k <<= 1) {
        #pragma unroll
        for (int r = 0; r < 4; r++) {
            ss0[r] += __shfl_xor(ss0[r], k, 64);
            cx0[r] = fmaxf(cx0[r], __shfl_xor(cx0[r], k, 64));
            ss1[r] += __shfl_xor(ss1[r], k, 64);
            cx1[r] = fmaxf(cx1[r], __shfl_xor(cx1[r], k, 64));
        }
    }

    float v_nll = 0.f, v_ent = 0.f, valid = 0.f;
    if (cn < 4) {
        #pragma unroll
        for (int tile = 0; tile < 2; tile++) {
            float T   = tile ? sel4(ss1, cn) : sel4(ss0, cn);
            float cxl = tile ? sel4(cx1, cn) : sel4(cx0, cn);
            float xts = tile ? sel4(xtr1, cn) : sel4(xtr0, cn);
            float Q   = tile ? sel4(Q1, cn) : sel4(Q0, cn);
            int lb    = tile ? isel4(lr1, cn) : isel4(lr0, cn);
            int pr = wavebase + g * 4 + cn + tile * 16;
            float u = __log2f(fmaxf(cxl, 1.f + EPSF));
            float nll = __logf(T) - Q + SLN * u;          // lse - logit_lab
            float pt = wsro[YT_OFF + lb], pn = wsro[XN_OFF + lb], ap = wsro[AP_OFF + lb];
            float num = fmaf(-cxl, pt, xts);              // y_time + c_xyl*x_time
            float den = pn * sqrtf(fmaxf(fmaf(cxl, cxl, -1.f), 0.f));
            float ain = fminf(fmaxf(num / (den + EPSF), -1.f + EPSF), 1.f - EPSF);
            float ent = fmaxf(acosf(ain) - ap, 0.f);
            float vl = mask[pr] ? 0.f : 1.f;
            v_nll += nll * vl; v_ent += ent * vl; valid += vl;
        }
    }

    #pragma unroll
    for (int o = 32; o >= 1; o >>= 1) {
        v_nll += __shfl_down(v_nll, o, 64);
        v_ent += __shfl_down(v_ent, o, 64);
        valid += __shfl_down(valid, o, 64);
    }
    __shared__ float red[3][4];
    if (lane == 0) { red[0][wid] = v_nll; red[1][wid] = v_ent; red[2][wid] = valid; }
    __syncthreads();
    if (tid == 0) {
        float a = 0.f, b = 0.f, c = 0.f;
        #pragma unroll
        for (int w = 0; w < 4; w++) { a += red[0][w]; b += red[1][w]; c += red[2][w]; }
        blkout[blockIdx.x] = make_float4(a, b, c, 0.f);
    }
}

__global__ __launch_bounds__(1024) void reduce_kernel(const float4* __restrict__ blk,
                                                      float* __restrict__ out) {
    float a = 0.f, b = 0.f, c = 0.f;
    for (int i = threadIdx.x; i < NBLK; i += 1024) {
        float4 v = blk[i];
        a += v.x; b += v.y; c += v.z;
    }
    #pragma unroll
    for (int o = 32; o >= 1; o >>= 1) {
        a += __shfl_down(a, o, 64);
        b += __shfl_down(b, o, 64);
        c += __shfl_down(c, o, 64);
    }
    __shared__ float red[3][16];
    int wid = threadIdx.x >> 6, lane = threadIdx.x & 63;
    if (lane == 0) { red[0][wid] = a; red[1][wid] = b; red[2][wid] = c; }
    __syncthreads();
    if (threadIdx.x == 0) {
        float A = 0.f, B = 0.f, C = 0.f;
        #pragma unroll
        for (int w = 0; w < 16; w++) { A += red[0][w]; B += red[1][w]; C += red[2][w]; }
        float n = fmaxf(C, 1.f);
        out[0] = A / n + ENTAIL_WEIGHT * (B / n);
    }
}

extern "C" void kernel_launch(void* const* d_in, const int* in_sizes, int n_in,
                              void* d_out, int out_size, void* d_ws, size_t ws_size,
                              hipStream_t stream) {
    const float* feats  = (const float*)d_in[0];
    const float* protos = (const float*)d_in[1];
    const int* labels   = (const int*)d_in[2];
    const unsigned char* mask = (const unsigned char*)d_in[3];  // numpy bool = 1 byte
    float* ws = (float*)d_ws;

    proto_kernel<<<1, 256, 0, stream>>>(protos, ws);

    int npix = in_sizes[2];                 // B*H*W = 524288
    int nblk = npix / 128;                  // 4 waves/block, 32 pixels/wave
    main_kernel<<<nblk, 256, 0, stream>>>(feats, labels, mask, ws,
                                          (float4*)(ws + BLK_OFF));
    reduce_kernel<<<1, 1024, 0, stream>>>((const float4*)(ws + BLK_OFF), (float*)d_out);
}

// Round 6
// 237.862 us; speedup vs baseline: 3.8089x; 1.0142x over previous
//
#include <hip/hip_runtime.h>
#include <math.h>

#define EPSF 1e-8f
#define SINH_MAXF 11.090354888959125f
#define IMAGE_ALPHA 0.25f
#define TEXT_ALPHA (1.0f/0.6f)
#define LOGIT_SCALE (1.0f/0.07f)
#define LN2F 0.6931471805599453f
#define SLN (LOGIT_SCALE*LN2F)
#define ENTAIL_WEIGHT 0.2f
#define NCLS 151
#define NPAD 160
#define DIM 64
#define NBLK 4096

// ws float offsets
#define LMIN_OFF 8   // log2(2*min_c y_time)
#define YT_OFF 16
#define XN_OFF (YT_OFF + NPAD)
#define AP_OFF (XN_OFF + NPAD)
#define BT_OFF 512                    // bf16 protos, MFMA-fragment order, 20480 B
#define BLK_OFF (BT_OFF + NPAD*DIM/2) // per-block float4 partials

typedef __attribute__((ext_vector_type(8))) short bf16x8;
typedef __attribute__((ext_vector_type(4))) float f32x4;

__device__ inline unsigned short f2bf(float f) {      // RNE (cold path only)
    unsigned int u = __float_as_uint(f);
    return (unsigned short)((u + 0x7FFFu + ((u >> 16) & 1u)) >> 16);
}
// pack trunc-bf16(hi) , trunc-bf16(lo) into one dword: 1 v_perm_b32
__device__ inline unsigned int pack_bf_trunc(float hi, float lo) {
    return __builtin_amdgcn_perm(__float_as_uint(hi), __float_as_uint(lo), 0x07060302u);
}
__device__ inline float sel4(const float* a, int i) {
    return i == 0 ? a[0] : i == 1 ? a[1] : i == 2 ? a[2] : a[3];
}
__device__ inline int isel4(const int* a, int i) {
    return i == 0 ? a[0] : i == 1 ? a[1] : i == 2 ? a[2] : a[3];
}

// Single block. Writes protos in MFMA B-fragment order:
// 16B unit index = t*128 + half*64 + (g*16+cn), element j: class t*16+cn, dim half*32+g*8+j
__global__ __launch_bounds__(256) void proto_kernel(const float* __restrict__ protos,
                                                    float* __restrict__ ws) {
    int tid = threadIdx.x, w = tid >> 6, l = tid & 63;
    unsigned short* bt = (unsigned short*)(ws + BT_OFF);
    __shared__ float sYT[NPAD];
    for (int c = w; c < NPAD; c += 4) {
        int t = c >> 4, cn = c & 15;
        int half = l >> 5, g = (l >> 3) & 3, j = l & 7;
        int sidx = (t * 128 + half * 64 + g * 16 + cn) * 8 + j;
        float yt_c;
        if (c < NCLS) {
            float v = protos[c * DIM + l] * TEXT_ALPHA;
            float n2 = v * v;
            #pragma unroll
            for (int m = 32; m >= 1; m >>= 1) n2 += __shfl_xor(n2, m, 64);
            float rc = __builtin_amdgcn_sqrtf(n2);
            float rr = fminf(fmaxf(rc, EPSF), SINH_MAXF);
            float e = __expf(rr);
            float sh = 0.5f * (e - __builtin_amdgcn_rcpf(e));
            float sc = sh * __builtin_amdgcn_rcpf(fmaxf(rc, EPSF));
            bt[sidx] = f2bf(sc * v);
            float xn = sc * rc;
            yt_c = __builtin_amdgcn_sqrtf(fmaf(xn, xn, 1.f));
            if (l == 0) {
                ws[YT_OFF + c] = yt_c;
                ws[XN_OFF + c] = xn;
                float ai = fminf(fmaxf(0.2f / (xn + EPSF), -1.f + EPSF), 1.f - EPSF);
                ws[AP_OFF + c] = asinf(ai);
            }
        } else {
            bt[sidx] = 0;
            yt_c = 2e18f;
            if (l == 0) { ws[YT_OFF + c] = 2e18f; ws[XN_OFF + c] = 1.f; ws[AP_OFF + c] = 0.f; }
        }
        if (l == 0) sYT[c] = yt_c;
    }
    __syncthreads();
    if (tid < 64) {
        float m = 1e30f;
        for (int c = tid; c < NCLS; c += 64) m = fminf(m, sYT[c]);
        #pragma unroll
        for (int k = 32; k >= 1; k >>= 1) m = fminf(m, __shfl_xor(m, k, 64));
        if (tid == 0) ws[LMIN_OFF] = __log2f(2.f * m);
    }
}

struct PixA { bf16x8 q0, q1; float xt, Q; };

__device__ inline PixA stage_pixel(const float4* fp, float lmin2) {
    float4 f0 = fp[0], f1 = fp[1], f2 = fp[8], f3 = fp[9];   // raw feats
    float n2r = f0.x*f0.x + f0.y*f0.y + f0.z*f0.z + f0.w*f0.w
              + f1.x*f1.x + f1.y*f1.y + f1.z*f1.z + f1.w*f1.w
              + f2.x*f2.x + f2.y*f2.y + f2.z*f2.z + f2.w*f2.w
              + f3.x*f3.x + f3.y*f3.y + f3.z*f3.z + f3.w*f3.w;
    n2r += __shfl_xor(n2r, 16, 64);
    n2r += __shfl_xor(n2r, 32, 64);      // 4 owner-lanes of this pixel have full ||feat||^2
    float rc = IMAGE_ALPHA * __builtin_amdgcn_sqrtf(n2r);   // ||alpha*feat||
    float rr = fminf(fmaxf(rc, EPSF), SINH_MAXF);
    float e = __expf(rr);
    float sh = 0.5f * (e - __builtin_amdgcn_rcpf(e));
    float sc = sh * __builtin_amdgcn_rcpf(fmaxf(rc, EPSF));
    float xn = sc * rc;
    float k = sc * IMAGE_ALPHA;          // combined scale on raw feats
    PixA r;
    r.xt = __builtin_amdgcn_sqrtf(fmaf(xn, xn, 1.f));
    // nat-domain constant: Q = M0 - SLN, M0 = -logit upper bound offset (see R5)
    r.Q = SLN * (lmin2 - __log2f(r.xt + xn)) - SLN;
    unsigned int* q0u = (unsigned int*)&r.q0;
    unsigned int* q1u = (unsigned int*)&r.q1;
    q0u[0] = pack_bf_trunc(k*f0.y, k*f0.x);
    q0u[1] = pack_bf_trunc(k*f0.w, k*f0.z);
    q0u[2] = pack_bf_trunc(k*f1.y, k*f1.x);
    q0u[3] = pack_bf_trunc(k*f1.w, k*f1.z);
    q1u[0] = pack_bf_trunc(k*f2.y, k*f2.x);
    q1u[1] = pack_bf_trunc(k*f2.w, k*f2.z);
    q1u[2] = pack_bf_trunc(k*f3.y, k*f3.x);
    q1u[3] = pack_bf_trunc(k*f3.w, k*f3.z);
    return r;
}

__global__ __launch_bounds__(256) void main_kernel(
    const float* __restrict__ feats, const int* __restrict__ labels,
    const unsigned char* __restrict__ mask, const float* __restrict__ wsro,
    float4* __restrict__ blkout)
{
    __shared__ uint4 sBT[1280];     // 20480 B, fragment order
    __shared__ float sYT[NPAD];
    int tid = threadIdx.x;
    const uint4* btg = (const uint4*)(wsro + BT_OFF);
    #pragma unroll
    for (int k = 0; k < 5; k++) sBT[tid + k * 256] = btg[tid + k * 256];
    if (tid < NPAD) sYT[tid] = wsro[YT_OFF + tid];
    __syncthreads();

    int wid = tid >> 6, lane = tid & 63;
    int cn = lane & 15, g = lane >> 4;
    int wavebase = (blockIdx.x * 4 + wid) * 32;
    int pix0 = wavebase + cn, pix1 = pix0 + 16;
    float lmin2 = wsro[LMIN_OFF];

    PixA A0 = stage_pixel((const float4*)(feats + (size_t)pix0 * DIM + g * 8), lmin2);
    PixA A1 = stage_pixel((const float4*)(feats + (size_t)pix1 * DIM + g * 8), lmin2);
    int lab0 = labels[pix0], lab1 = labels[pix1];

    float xtr0[4], Q0[4], xtr1[4], Q1[4];
    int lr0[4], lr1[4];
    #pragma unroll
    for (int r = 0; r < 4; r++) {
        int src = g * 4 + r;
        xtr0[r] = __shfl(A0.xt, src, 64); Q0[r] = __shfl(A0.Q, src, 64);
        lr0[r]  = __shfl(lab0, src, 64);
        xtr1[r] = __shfl(A1.xt, src, 64); Q1[r] = __shfl(A1.Q, src, 64);
        lr1[r]  = __shfl(lab1, src, 64);
    }

    float ss0[4] = {0,0,0,0}, ss1[4] = {0,0,0,0};
    float sv0[4] = {0,0,0,0}, sv1[4] = {0,0,0,0};   // label-z saved on owning lane

    #pragma unroll 2
    for (int t = 0; t < 10; t++) {
        uint4 u0 = sBT[t * 128 + lane];
        uint4 u1 = sBT[t * 128 + 64 + lane];
        bf16x8 bq0 = __builtin_bit_cast(bf16x8, u0);
        bf16x8 bq1 = __builtin_bit_cast(bf16x8, u1);
        float yt = sYT[t * 16 + cn];
        int cls = t * 16 + cn;
        f32x4 d0 = {0,0,0,0}, d1 = {0,0,0,0};
        d0 = __builtin_amdgcn_mfma_f32_16x16x32_bf16(A0.q0, bq0, d0, 0, 0, 0);
        d0 = __builtin_amdgcn_mfma_f32_16x16x32_bf16(A0.q1, bq1, d0, 0, 0, 0);
        d1 = __builtin_amdgcn_mfma_f32_16x16x32_bf16(A1.q0, bq0, d1, 0, 0, 0);
        d1 = __builtin_amdgcn_mfma_f32_16x16x32_bf16(A1.q1, bq1, d1, 0, 0, 0);
        #pragma unroll
        for (int r = 0; r < 4; r++) {
            float c0 = fmaf(xtr0[r], yt, -d0[r]);         // z = x_time*y_time - dot  (>= ~9e4)
            if (lr0[r] == cls) sv0[r] = c0;
            ss0[r] += __expf(fmaf(-SLN, __log2f(c0), Q0[r]));  // exp(logit - M0)
            float c1 = fmaf(xtr1[r], yt, -d1[r]);
            if (lr1[r] == cls) sv1[r] = c1;
            ss1[r] += __expf(fmaf(-SLN, __log2f(c1), Q1[r]));
        }
    }

    // sum-reduce ss across the 16-lane class dim; fetch label-z via one bpermute
    int gbase = lane & 48;
    float cx0[4], cx1[4];
    #pragma unroll
    for (int r = 0; r < 4; r++) {
        cx0[r] = __shfl(sv0[r], gbase + (lr0[r] & 15), 64);
        cx1[r] = __shfl(sv1[r], gbase + (lr1[r] & 15), 64);
    }
    #pragma unroll
    for (int k = 1; k < 16; k <<= 1) {
        #pragma unroll
        for (int r = 0; r < 4; r++) {
            ss0[r] += __shfl_xor(ss0[r], k, 64);
            ss1[r] += __shfl_xor(ss1[r], k, 64);
        }
    }

    float v_nll = 0.f, v_ent = 0.f, valid = 0.f;
    if (cn < 4) {
        #pragma unroll
        for (int tile = 0; tile < 2; tile++) {
            float T   = tile ? sel4(ss1, cn) : sel4(ss0, cn);
            float cxl = tile ? sel4(cx1, cn) : sel4(cx0, cn);
            float xts = tile ? sel4(xtr1, cn) : sel4(xtr0, cn);
            float Q   = tile ? sel4(Q1, cn) : sel4(Q0, cn);
            int lb    = tile ? isel4(lr1, cn) : isel4(lr0, cn);
            int pr = wavebase + g * 4 + cn + tile * 16;
            float nll = __logf(T) - Q + SLN * __log2f(cxl);   // lse - logit_lab
            float pt = wsro[YT_OFF + lb], pn = wsro[XN_OFF + lb], ap = wsro[AP_OFF + lb];
            float num = fmaf(-cxl, pt, xts);                  // y_time + c_xyl*x_time
            float den = pn * __builtin_amdgcn_sqrtf(fmaxf(fmaf(cxl, cxl, -1.f), 0.f));
            float ain = num * __builtin_amdgcn_rcpf(den + EPSF);
            ain = fminf(fmaxf(ain, -1.f + EPSF), 1.f - EPSF);
            // branchless acos: A&S 4.4.45, |err| <= 6.7e-5 rad
            float ax = fabsf(ain);
            float p = fmaf(fmaf(fmaf(-0.0187293f, ax, 0.0742610f), ax, -0.2121144f),
                           ax, 1.5707288f);
            float rr = __builtin_amdgcn_sqrtf(1.f - ax) * p;
            float ac = ain < 0.f ? 3.14159265358979f - rr : rr;
            float ent = fmaxf(ac - ap, 0.f);
            float vl = mask[pr] ? 0.f : 1.f;
            v_nll += nll * vl; v_ent += ent * vl; valid += vl;
        }
    }

    #pragma unroll
    for (int o = 32; o >= 1; o >>= 1) {
        v_nll += __shfl_down(v_nll, o, 64);
        v_ent += __shfl_down(v_ent, o, 64);
        valid += __shfl_down(valid, o, 64);
    }
    __shared__ float red[3][4];
    if (lane == 0) { red[0][wid] = v_nll; red[1][wid] = v_ent; red[2][wid] = valid; }
    __syncthreads();
    if (tid == 0) {
        float a = 0.f, b = 0.f, c = 0.f;
        #pragma unroll
        for (int w = 0; w < 4; w++) { a += red[0][w]; b += red[1][w]; c += red[2][w]; }
        blkout[blockIdx.x] = make_float4(a, b, c, 0.f);
    }
}

__global__ __launch_bounds__(1024) void reduce_kernel(const float4* __restrict__ blk,
                                                      float* __restrict__ out) {
    float a = 0.f, b = 0.f, c = 0.f;
    for (int i = threadIdx.x; i < NBLK; i += 1024) {
        float4 v = blk[i];
        a += v.x; b += v.y; c += v.z;
    }
    #pragma unroll
    for (int o = 32; o >= 1; o >>= 1) {
        a += __shfl_down(a, o, 64);
        b += __shfl_down(b, o, 64);
        c += __shfl_down(c, o, 64);
    }
    __shared__ float red[3][16];
    int wid = threadIdx.x >> 6, lane = threadIdx.x & 63;
    if (lane == 0) { red[0][wid] = a; red[1][wid] = b; red[2][wid] = c; }
    __syncthreads();
    if (threadIdx.x == 0) {
        float A = 0.f, B = 0.f, C = 0.f;
        #pragma unroll
        for (int w = 0; w < 16; w++) { A += red[0][w]; B += red[1][w]; C += red[2][w]; }
        float n = fmaxf(C, 1.f);
        out[0] = A / n + ENTAIL_WEIGHT * (B / n);
    }
}

extern "C" void kernel_launch(void* const* d_in, const int* in_sizes, int n_in,
                              void* d_out, int out_size, void* d_ws, size_t ws_size,
                              hipStream_t stream) {
    const float* feats  = (const float*)d_in[0];
    const float* protos = (const float*)d_in[1];
    const int* labels   = (const int*)d_in[2];
    const unsigned char* mask = (const unsigned char*)d_in[3];  // numpy bool = 1 byte
    float* ws = (float*)d_ws;

    proto_kernel<<<1, 256, 0, stream>>>(protos, ws);

    int npix = in_sizes[2];                 // B*H*W = 524288
    int nblk = npix / 128;                  // 4 waves/block, 32 pixels/wave
    main_kernel<<<nblk, 256, 0, stream>>>(feats, labels, mask, ws,
                                          (float4*)(ws + BLK_OFF));
    reduce_kernel<<<1, 1024, 0, stream>>>((const float4*)(ws + BLK_OFF), (float*)d_out);
}